// Round 1
// baseline (124657.166 us; speedup 1.0000x reference)
//
// Round 1: correctness-first persistent cooperative kernel.
// Pipelined supersteps: s computes L1@t=s, L2@t=s-1, L3@t=s-2 (phase A);
// attention@t=s + output-projection@t=s-2 (phase B). 2 grid.sync per superstep.
// All fp32. State kept transposed [feat][batch] in d_ws (~2 MB).

#include <hip/hip_runtime.h>
#include <hip/hip_cooperative_groups.h>

namespace cg = cooperative_groups;

// Problem constants (match setup_inputs)
#define HB   400
#define KK   10
#define VV   77
#define OO   121
#define BB   64
#define TT   600
#define UU   64

#define NTHREADS 65536   // 256 WG * 256 thr
#define HBSTRIDE 25600   // H*B
#define WSTRIDE  4928    // V*B

struct Args {
  const float* __restrict__ x;
  const int*   __restrict__ text;
  const float* __restrict__ mask;
  const float* __restrict__ Wih1; const float* __restrict__ Whh1; const float* __restrict__ b1;
  const float* __restrict__ Wih2; const float* __restrict__ Whh2; const float* __restrict__ b2;
  const float* __restrict__ Wih3; const float* __restrict__ Whh3; const float* __restrict__ b3;
  const float* __restrict__ Wwin; const float* __restrict__ bwin;
  const float* __restrict__ Wout; const float* __restrict__ bout;
  float* __restrict__ out;
  float* __restrict__ ws;
};

__device__ __forceinline__ float sigm(float v) { return 1.0f / (1.0f + __expf(-v)); }

// One LSTM cell update for hidden unit j, batch b: computes all 4 gates.
// Wih layout (4H, LD): cols [0..2]=x, (HASH1: [3..402]=h1, [403..479]=w) else [3..79]=w.
template<int LD, bool HASH1>
__attribute__((noinline)) __device__ void lstm_cell(
    int j, int b,
    const float* __restrict__ Wih, const float* __restrict__ Whh,
    const float* __restrict__ bias,
    float x0, float x1, float x2,
    const float* __restrict__ h1in,   // (H,B) or unused
    const float* __restrict__ win,    // (V,B)
    const float* __restrict__ hin,    // (H,B) own previous h
    float* __restrict__ cptr, float* __restrict__ hptr)
{
  const float* w0 = Wih + j * LD;
  const float* w1 = Wih + (400 + j) * LD;
  const float* w2 = Wih + (800 + j) * LD;
  const float* w3 = Wih + (1200 + j) * LD;
  float a0 = bias[j]        + w0[0]*x0 + w0[1]*x1 + w0[2]*x2;
  float a1 = bias[400 + j]  + w1[0]*x0 + w1[1]*x1 + w1[2]*x2;
  float a2 = bias[800 + j]  + w2[0]*x0 + w2[1]*x1 + w2[2]*x2;
  float a3 = bias[1200 + j] + w3[0]*x0 + w3[1]*x1 + w3[2]*x2;
  int off = 3;
  if constexpr (HASH1) {
    #pragma unroll 4
    for (int k = 0; k < HB; ++k) {
      float v = h1in[k * BB + b];
      a0 += w0[3 + k] * v; a1 += w1[3 + k] * v; a2 += w2[3 + k] * v; a3 += w3[3 + k] * v;
    }
    off = 403;
  }
  #pragma unroll 7
  for (int k = 0; k < VV; ++k) {
    float v = win[k * BB + b];
    a0 += w0[off + k] * v; a1 += w1[off + k] * v; a2 += w2[off + k] * v; a3 += w3[off + k] * v;
  }
  const float* u0 = Whh + j * HB;
  const float* u1 = Whh + (400 + j) * HB;
  const float* u2 = Whh + (800 + j) * HB;
  const float* u3 = Whh + (1200 + j) * HB;
  #pragma unroll 4
  for (int k = 0; k < HB; ++k) {
    float v = hin[k * BB + b];
    a0 += u0[k] * v; a1 += u1[k] * v; a2 += u2[k] * v; a3 += u3[k] * v;
  }
  float ig = sigm(a0), fg = sigm(a1), gg = tanhf(a2), og = sigm(a3);
  float cn = fg * (*cptr) + ig * gg;
  *cptr = cn;
  *hptr = og * tanhf(cn);
}

// Item -> (layer, cell) permutation. 76800 items; threads tid<11264 take a 2nd
// item at tid+65536. Both of a doubled thread's items are (cheap) L1 cells.
// All region boundaries are multiples of 64 so b == lane, j wave-uniform.
__device__ __forceinline__ void phaseA_item(const Args& A, int s, int p,
    float* h1r, float* h2r, float* h3r, float* c1, float* c2, float* c3,
    float* wrng, const float* xT)
{
  int layer, cid;
  if (p < 11264)       { layer = 1; cid = p; }
  else if (p >= 65536) { layer = 1; cid = p - 54272; }
  else {
    int q = p - 11264;
    if (q < 3072)       { layer = 1; cid = 22528 + q; }
    else if (q < 28672) { layer = 2; cid = q - 3072; }
    else                { layer = 3; cid = q - 28672; }
  }
  int b = cid & 63;
  int j = __builtin_amdgcn_readfirstlane(cid >> 6);

  if (layer == 1) {
    if (s >= TT) return;
    int t = s;
    const float* xt = xT + t * 3 * BB;
    lstm_cell<80, false>(j, b, A.Wih1, A.Whh1, A.b1,
        xt[b], xt[BB + b], xt[2 * BB + b],
        nullptr,
        wrng + ((t - 1) & 3) * WSTRIDE,
        h1r + ((t - 1) & 3) * HBSTRIDE,
        c1 + (j * BB + b),
        h1r + (t & 3) * HBSTRIDE + j * BB + b);
  } else if (layer == 2) {
    if (s < 1 || s > TT) return;
    int t = s - 1;
    const float* xt = xT + t * 3 * BB;
    lstm_cell<480, true>(j, b, A.Wih2, A.Whh2, A.b2,
        xt[b], xt[BB + b], xt[2 * BB + b],
        h1r + (t & 3) * HBSTRIDE,
        wrng + (t & 3) * WSTRIDE,
        h2r + ((t - 1) & 3) * HBSTRIDE,
        c2 + (j * BB + b),
        h2r + (t & 3) * HBSTRIDE + j * BB + b);
  } else {
    if (s < 2) return;
    int t = s - 2;
    const float* xt = xT + t * 3 * BB;
    lstm_cell<480, true>(j, b, A.Wih3, A.Whh3, A.b3,
        xt[b], xt[BB + b], xt[2 * BB + b],
        h2r + (t & 3) * HBSTRIDE,
        wrng + (t & 3) * WSTRIDE,
        h3r + ((t - 1) & 3) * HBSTRIDE,
        c3 + (j * BB + b),
        h3r + (t & 3) * HBSTRIDE + j * BB + b);
  }
}

__global__ __launch_bounds__(256) void hsnet_kernel(Args A) {
  cg::grid_group grid = cg::this_grid();
  const int lid = threadIdx.x;
  const int wg  = blockIdx.x;
  const int tid = wg * 256 + lid;

  // Workspace layout (floats)
  float* h1r  = A.ws;                    // 4 * 25600
  float* h2r  = h1r + 4 * HBSTRIDE;      // 4 * 25600
  float* h3r  = h2r + 4 * HBSTRIDE;      // 4 * 25600
  float* c1   = h3r + 4 * HBSTRIDE;      // 25600
  float* c2   = c1 + HBSTRIDE;
  float* c3   = c2 + HBSTRIDE;
  float* wrng = c3 + HBSTRIDE;           // 4 * 4928
  float* kap  = wrng + 4 * WSTRIDE;      // 640
  float* xT   = kap + KK * BB;           // 600*3*64 = 115200

  __shared__ float sred[240];
  __shared__ float smix[30];
  __shared__ float skap[KK];
  __shared__ float sphi[UU];
  __shared__ int   stext[UU];
  __shared__ float swv[VV];

  // ---- prologue: zero state, transpose x to (T,3,B) ----
  for (int i = tid; i < 404352; i += NTHREADS) A.ws[i] = 0.0f;
  for (int i = tid; i < TT * 3 * BB; i += NTHREADS) {
    int b = i & 63; int tj = i >> 6; int t = tj / 3; int jj = tj - t * 3;
    xT[i] = A.x[(b * TT + t) * 3 + jj];
  }
  __threadfence();
  grid.sync();

  for (int s = 0; s < TT + 2; ++s) {
    // ---------- phase A: LSTM cells, pipelined across layers ----------
    phaseA_item(A, s, tid, h1r, h2r, h3r, c1, c2, c3, wrng, xT);
    if (tid < 11264)
      phaseA_item(A, s, tid + 65536, h1r, h2r, h3r, c1, c2, c3, wrng, xT);
    __threadfence();
    grid.sync();

    // ---------- phase B: attention (WG 0..63) + out-proj (WG 64..255) ----------
    if (wg < BB) {
      if (s < TT) {
        const int b = wg;
        const float* h1t = h1r + (s & 3) * HBSTRIDE;
        if (lid < 240) {
          int g = lid >> 3, part = lid & 7;
          const float* wr = A.Wwin + g * HB;
          float acc = 0.0f;
          int k0 = part * 50;
          #pragma unroll 5
          for (int k = k0; k < k0 + 50; ++k) acc += wr[k] * h1t[k * BB + b];
          sred[lid] = acc;
        }
        if (lid < UU) stext[lid] = A.text[b * UU + lid];
        __syncthreads();
        if (lid < 30) {
          float m = A.bwin[lid];
          #pragma unroll
          for (int p2 = 0; p2 < 8; ++p2) m += sred[lid * 8 + p2];
          smix[lid] = __expf(m);  // alpha/beta/kappa all exp()ed
        }
        __syncthreads();
        if (lid < KK) {
          float kn = kap[lid * BB + b] + smix[20 + lid];
          kap[lid * BB + b] = kn;
          skap[lid] = kn;
        }
        __syncthreads();
        if (lid < UU) {
          float u = (float)lid;
          float phi = 0.0f;
          #pragma unroll
          for (int k = 0; k < KK; ++k) {
            float d = skap[k] - u;
            phi += smix[k] * __expf(-smix[10 + k] * d * d);
          }
          phi *= A.mask[b * UU + lid];
          sphi[lid] = phi;
        }
        __syncthreads();
        if (lid < VV) {
          float acc = 0.0f;
          for (int u2 = 0; u2 < UU; ++u2)
            acc += (stext[u2] == lid) ? sphi[u2] : 0.0f;
          wrng[(s & 3) * WSTRIDE + lid * BB + b] = acc;
        }
      }
    } else if (s >= 2) {
      const int t = s - 2;
      int tt3 = (wg - 64) * 256 + lid;
      if (tt3 < OO * BB) {
        int o = __builtin_amdgcn_readfirstlane(tt3 >> 6);
        int b = tt3 & 63;
        int slot = t & 3;
        const float* wr  = A.Wout + o * 1200;
        const float* h1t = h1r + slot * HBSTRIDE;
        const float* h2t = h2r + slot * HBSTRIDE;
        const float* h3t = h3r + slot * HBSTRIDE;
        float acc = A.bout[o];
        #pragma unroll 4
        for (int k = 0; k < HB; ++k) acc += wr[k]       * h1t[k * BB + b];
        #pragma unroll 4
        for (int k = 0; k < HB; ++k) acc += wr[400 + k] * h2t[k * BB + b];
        #pragma unroll 4
        for (int k = 0; k < HB; ++k) acc += wr[800 + k] * h3t[k * BB + b];
        A.out[(b * TT + t) * OO + o] = acc;
      }
    }
    __threadfence();
    grid.sync();
  }
}

extern "C" void kernel_launch(void* const* d_in, const int* in_sizes, int n_in,
                              void* d_out, int out_size, void* d_ws, size_t ws_size,
                              hipStream_t stream) {
  Args a;
  a.x    = (const float*)d_in[0];
  a.text = (const int*)  d_in[1];
  a.mask = (const float*)d_in[2];
  a.Wih1 = (const float*)d_in[3];  a.Whh1 = (const float*)d_in[4];  a.b1 = (const float*)d_in[5];
  a.Wih2 = (const float*)d_in[6];  a.Whh2 = (const float*)d_in[7];  a.b2 = (const float*)d_in[8];
  a.Wih3 = (const float*)d_in[9];  a.Whh3 = (const float*)d_in[10]; a.b3 = (const float*)d_in[11];
  a.Wwin = (const float*)d_in[12]; a.bwin = (const float*)d_in[13];
  a.Wout = (const float*)d_in[14]; a.bout = (const float*)d_in[15];
  a.out  = (float*)d_out;
  a.ws   = (float*)d_ws;
  void* kargs[] = { &a };
  hipLaunchCooperativeKernel((const void*)hsnet_kernel, dim3(256), dim3(256),
                             kargs, 0, stream);
}